// Round 5
// baseline (272.892 us; speedup 1.0000x reference)
//
#include <hip/hip_runtime.h>
#include <hip/hip_bf16.h>
#include <hip/hip_fp16.h>

// GCN: h1 = relu(GCNConv(x,W1,b1)); h2 = GCNConv(h1,W2,b2);
//      h3 = relu(h2@Wm1+bm1); out = h3@Wm2+bm2
// R2: CSR-by-dst gather-reduce replaced scatter atomics (10x write amp).
// R4: 2-pass XCD-local bucket sort. R5: dinv folded into GEMM epilogue.
// R6/R8 FAILED: multi-phase LDS GEMM fusion -> spills. R7: fp16 g-tables.
// R9: 2-node/wave aggregate, 8-deep (255.8us). R13 FAILED: 4-deep (263us).
// R14: cleanup (253.7us). R15 FAILED (1071us): scatter-side LDS agg -- 16x
//      fewer waves; binding resource is latency-hiding slack. R16 FAILED
//      (268.5us): perm pairing. R17 NEUTRAL (252.2us): depth 8->16;
//      pipeline saturates at 8.
// R18 WIN (249.0us): per-row 64x64 GEMM fused into aggregate epilogues;
//      killed 2 GEMM dispatches + hB traffic. But agg 42->53.7us: epilogue
//      adds issue pressure (VALU 43%, HBM 20%, occ 60% -- issue-bound
//      across VALU/LDS/VMEM, no pipe saturated).
// R19: instruction diet on agg_fused. (a) dual-row b64 gathers: 16-lane
//      groups, one gather instr fetches TWO edges' rows (16->8 vmem/trip,
//      depth still 8); shfl_xor(16) cross-group reduce. (b) transposed
//      Wt[64][65] in LDS: epilogue 96 ds_b64 -> 48 ds_b128 (2-way alias
//      = free). Cache-line traffic unchanged -- tests "issue-bound" theory.

namespace {

constexpr int N_NODES = 100000;
constexpr int N_EDGES = 1000000;
constexpr int NBUCK = (N_NODES + 511) / 512;  // 196 buckets of 512 nodes
constexpr int CAP_RAW = 8192;   // raw edges/bucket (mean 5120, sd ~71)
constexpr int CAP_COL = 12288;  // pad-16 edges/bucket (mean ~8400, sd ~80)
constexpr int EPB_A = 2048;     // edges per passA block

// passA: partition edges into NBUCK buckets by dst>>9. word=(src<<9)|(dst&511).
__global__ __launch_bounds__(256) void bucket_kernel(const void* __restrict__ ei,
                                                     int* __restrict__ bucketCnt,
                                                     unsigned* __restrict__ tmp) {
  __shared__ int hist[NBUCK];
  __shared__ int basePB[NBUCK];
  __shared__ int cur[NBUCK];
  __shared__ int sflag;
  int t = threadIdx.x;
  if (t < NBUCK) { hist[t] = 0; cur[t] = 0; }
  if (t == 0) sflag = 0;
  __syncthreads();

  int e0 = blockIdx.x * EPB_A;
  const unsigned* w = (const unsigned*)ei;
  unsigned any = 0;
#pragma unroll
  for (int s = 0; s < 2; s++) {
    int e = e0 + s * 256 + t;
    if (e < N_EDGES) any |= w[2 * e + 1];
  }
  if (any) sflag = 1;  // benign race, all writers store 1
  __syncthreads();
  int is32 = sflag;

  unsigned wreg[8];
  int breg[8];
#pragma unroll
  for (int k = 0; k < 8; k++) {
    int e = e0 + k * 256 + t;
    breg[k] = -1;
    if (e < N_EDGES) {
      int s, d;
      if (is32) {
        const int* p = (const int*)ei;
        s = p[e]; d = p[N_EDGES + e];
      } else {
        const long long* p = (const long long*)ei;
        s = (int)p[e]; d = (int)p[N_EDGES + e];
      }
      wreg[k] = ((unsigned)s << 9) | (unsigned)(d & 511);
      breg[k] = d >> 9;
      atomicAdd(&hist[breg[k]], 1);
    }
  }
  __syncthreads();
  if (t < NBUCK) basePB[t] = hist[t] ? atomicAdd(&bucketCnt[t], hist[t]) : 0;
  __syncthreads();
#pragma unroll
  for (int k = 0; k < 8; k++) {
    if (breg[k] >= 0) {
      int r = atomicAdd(&cur[breg[k]], 1);
      tmp[(size_t)breg[k] * CAP_RAW + basePB[breg[k]] + r] = wreg[k];
    }
  }
}

// passB: one block per bucket. LDS counting sort; rows padded to mult 16 with
// sentinel N_NODES (zero row); emit row_start/row_end + dinv.
__global__ __launch_bounds__(512) void csr_kernel(const unsigned* __restrict__ tmp,
                                                  const int* __restrict__ bucketCnt,
                                                  int* __restrict__ col,
                                                  int* __restrict__ row_start,
                                                  int* __restrict__ row_end,
                                                  float* __restrict__ dinv) {
  __shared__ int sc[512];
  __shared__ int hist[512];
  __shared__ unsigned stage[CAP_RAW];
  int b = blockIdx.x, t = threadIdx.x;
  int myCnt = bucketCnt[b];
  int baseT = b * CAP_RAW;
  int baseC = b * CAP_COL;

  hist[t] = 0;
  __syncthreads();
  for (int i = t; i < myCnt; i += 512) {
    unsigned w = tmp[(size_t)baseT + i];
    stage[i] = w;
    atomicAdd(&hist[w & 511u], 1);
  }
  __syncthreads();

  int deg = hist[t];
  int pdeg = (deg + 15) & ~15;  // pad rows to mult 16 (16-deep pipeline)
  sc[t] = pdeg;
  __syncthreads();
#pragma unroll
  for (int off = 1; off < 512; off <<= 1) {
    int u = (t >= off) ? sc[t - off] : 0;
    __syncthreads();
    sc[t] += u;
    __syncthreads();
  }
  int pexcl = sc[t] - pdeg;
  int d = b * 512 + t;
  if (d < N_NODES) {
    row_start[d] = baseC + pexcl;
    row_end[d] = baseC + pexcl + pdeg;
    dinv[d] = rsqrtf((float)deg + 1.0f);
  }
  __syncthreads();
  hist[t] = pexcl;
  __syncthreads();
  for (int i = t; i < myCnt; i += 512) {
    unsigned w = stage[i];
    int pos = atomicAdd(&hist[w & 511u], 1);
    col[baseC + pos] = (int)(w >> 9);
  }
  for (int j = deg; j < pdeg; j++) col[baseC + pexcl + j] = N_NODES;
}

__device__ inline uint4 pack_half8(const float* v) {
  __half2 h0 = __floats2half2_rn(v[0], v[1]);
  __half2 h1 = __floats2half2_rn(v[2], v[3]);
  __half2 h2 = __floats2half2_rn(v[4], v[5]);
  __half2 h3 = __floats2half2_rn(v[6], v[7]);
  uint4 u;
  u.x = *(unsigned*)&h0; u.y = *(unsigned*)&h1;
  u.z = *(unsigned*)&h2; u.w = *(unsigned*)&h3;
  return u;
}

// g[r] = (op(A[r])@W) * dinv[r], fp16 out, zero pad row N_NODES.
// 128 rows/block, 256 thr, thread = 4 rows x 8 cols. W staged in LDS.
__global__ __launch_bounds__(256) void gemm_g_kernel(const float* __restrict__ A,
                                                     const float* __restrict__ W,
                                                     const float* __restrict__ dinv,
                                                     __half* __restrict__ g,
                                                     __half* __restrict__ gpad2,
                                                     int reluIn) {
  __shared__ float Ws[64 * 64];
  int t = threadIdx.x;
  if (blockIdx.x == 0 && t < 32) {
    ((float*)(g + (size_t)N_NODES * 64))[t] = 0.f;  // pad row (this table)
    if (gpad2) ((float*)(gpad2 + (size_t)N_NODES * 64))[t] = 0.f;  // pad row (agg1 output table)
  }
  for (int i = t; i < 64 * 64 / 4; i += 256) ((float4*)Ws)[i] = ((const float4*)W)[i];
  __syncthreads();

  int rg = t >> 3, cg = t & 7;
  int r0 = blockIdx.x * 128 + rg * 4;
  int c0 = cg * 8;

  float acc[4][8];
#pragma unroll
  for (int i = 0; i < 4; i++)
#pragma unroll
    for (int j = 0; j < 8; j++) acc[i][j] = 0.f;

  const float4* A4 = (const float4*)A;
  for (int kk = 0; kk < 16; kk++) {
    float4 a[4];
#pragma unroll
    for (int i = 0; i < 4; i++) {
      int r = r0 + i;
      float4 v = (r < N_NODES) ? A4[(size_t)r * 16 + kk] : make_float4(0.f, 0.f, 0.f, 0.f);
      if (reluIn) {
        v.x = fmaxf(v.x, 0.f); v.y = fmaxf(v.y, 0.f);
        v.z = fmaxf(v.z, 0.f); v.w = fmaxf(v.w, 0.f);
      }
      a[i] = v;
    }
#pragma unroll
    for (int q = 0; q < 4; q++) {
      int k = kk * 4 + q;
      float w[8];
#pragma unroll
      for (int j = 0; j < 2; j++) *(float4*)&w[4 * j] = *(const float4*)&Ws[k * 64 + c0 + 4 * j];
#pragma unroll
      for (int i = 0; i < 4; i++) {
        float av = q == 0 ? a[i].x : q == 1 ? a[i].y : q == 2 ? a[i].z : a[i].w;
#pragma unroll
        for (int j = 0; j < 8; j++) acc[i][j] = fmaf(av, w[j], acc[i][j]);
      }
    }
  }
#pragma unroll
  for (int i = 0; i < 4; i++) {
    int r = r0 + i;
    if (r < N_NODES) {
      float s = dinv[r];
#pragma unroll
      for (int j = 0; j < 8; j++) acc[i][j] *= s;
      *(uint4*)(g + (size_t)r * 64 + c0) = pack_half8(acc[i]);
    }
  }
}

// Fused gather-aggregate + per-row 64x64 GEMM epilogue (R18/R19).
// Gather phase (R19): half-wave = one node; two 16-lane groups; lane loads
// b64 (4 feats), so ONE gather instr fetches TWO edges' rows (group 0 = even
// edge, group 1 = odd). 8 gather instrs per 16-edge trip (depth 8, R9-proven).
// Cross-group reduce: shfl_xor(16). Sentinel pad rows hit the zero row.
// Epilogue: row h staged in per-half-wave LDS slot; each lane computes cols
// {2*sub, 2*sub+1} from transposed Wt[64][65] with b128 k-runs (48 ds_b128).
// MODE 1 (conv1 -> conv2 g-table): relu(h) pre-GEMM, *dinv post, fp16 out.
// MODE 2 (conv2 -> MLP hidden):    no pre-relu, +bpost then relu, fp32 out.
template <int MODE>
__global__ __launch_bounds__(256) void agg_fused(const __half* __restrict__ g,
                                                 const int* __restrict__ col,
                                                 const int* __restrict__ row_start,
                                                 const int* __restrict__ row_end,
                                                 const float* __restrict__ dinv,
                                                 const float* __restrict__ bconv,
                                                 const float* __restrict__ W,
                                                 const float* __restrict__ bpost,
                                                 void* __restrict__ outp) {
  __shared__ float Wt[64][65];    // transposed+padded: Wt[c][k] = W[k][c]
  __shared__ float rows[8][64];   // one row slot per half-wave
  int t = threadIdx.x;
  for (int i = t; i < 64 * 64; i += 256) {
    int k = i >> 6, c = i & 63;
    Wt[c][k] = W[i];  // coalesced global read; conflict-free LDS write
  }
  __syncthreads();

  int wave = t >> 6;
  int lane = t & 63;
  int half = lane >> 5;
  int sub = lane & 31;
  int gq = (lane >> 4) & 1;  // 16-lane group within half-wave
  int w16 = lane & 15;       // covers feats 4*w16 .. 4*w16+3
  int slot = t >> 5;         // half-wave id 0..7
  int d = blockIdx.x * 8 + wave * 2 + half;

  const uint2* gu = (const uint2*)g;  // b64 units: row r feats 4j.. at gu[r*16+j]
  int e0 = row_start[d];
  int len = row_end[d] - e0;

  uint2 uself = gu[(size_t)d * 16 + w16];  // self row (dinv folded in g)

  float s0 = 0.f, s1 = 0.f, s2 = 0.f, s3 = 0.f;  // this group's edge partials

  for (int i = 0; i < len; i += 16) {  // per-half-wave trip count
    int4 ca = *(const int4*)(col + e0 + i);
    int4 cb = *(const int4*)(col + e0 + i + 4);
    int4 cc = *(const int4*)(col + e0 + i + 8);
    int4 cd = *(const int4*)(col + e0 + i + 12);
    int r0 = gq ? ca.y : ca.x;
    int r1 = gq ? ca.w : ca.z;
    int r2 = gq ? cb.y : cb.x;
    int r3 = gq ? cb.w : cb.z;
    int r4 = gq ? cc.y : cc.x;
    int r5 = gq ? cc.w : cc.z;
    int r6 = gq ? cd.y : cd.x;
    int r7 = gq ? cd.w : cd.z;
    uint2 u0 = gu[(size_t)r0 * 16 + w16];
    uint2 u1 = gu[(size_t)r1 * 16 + w16];
    uint2 u2 = gu[(size_t)r2 * 16 + w16];
    uint2 u3 = gu[(size_t)r3 * 16 + w16];
    uint2 u4 = gu[(size_t)r4 * 16 + w16];
    uint2 u5 = gu[(size_t)r5 * 16 + w16];
    uint2 u6 = gu[(size_t)r6 * 16 + w16];
    uint2 u7 = gu[(size_t)r7 * 16 + w16];
#define ACC(u)                                              \
  {                                                         \
    float2 flo = __half22float2(*(const __half2*)&(u).x);   \
    float2 fhi = __half22float2(*(const __half2*)&(u).y);   \
    s0 += flo.x; s1 += flo.y; s2 += fhi.x; s3 += fhi.y;     \
  }
    ACC(u0) ACC(u1) ACC(u2) ACC(u3) ACC(u4) ACC(u5) ACC(u6) ACC(u7)
#undef ACC
  }
  // cross-group reduce: lane w16 (+0/+16) hold same-feature partials
  s0 += __shfl_xor(s0, 16, 64);
  s1 += __shfl_xor(s1, 16, 64);
  s2 += __shfl_xor(s2, 16, 64);
  s3 += __shfl_xor(s3, 16, 64);
  {  // add self
    float2 flo = __half22float2(*(const __half2*)&uself.x);
    float2 fhi = __half22float2(*(const __half2*)&uself.y);
    s0 += flo.x; s1 += flo.y; s2 += fhi.x; s3 += fhi.y;
  }
  float dv = dinv[d];
  float4 bv = *(const float4*)&bconv[4 * w16];
  float h0 = fmaf(s0, dv, bv.x);
  float h1 = fmaf(s1, dv, bv.y);
  float h2 = fmaf(s2, dv, bv.z);
  float h3 = fmaf(s3, dv, bv.w);
  if (MODE == 1) {
    h0 = fmaxf(h0, 0.f); h1 = fmaxf(h1, 0.f);
    h2 = fmaxf(h2, 0.f); h3 = fmaxf(h3, 0.f);
  }

  // stage row (group 0 only; wave-synchronous, same-wave LDS ordering)
  if (gq == 0) *(float4*)&rows[slot][4 * w16] = make_float4(h0, h1, h2, h3);

  // epilogue matvec: lane computes cols 2*sub, 2*sub+1; b128 k-runs.
  float o0 = 0.f, o1 = 0.f;
  int c0 = 2 * sub, c1 = 2 * sub + 1;
#pragma unroll 4
  for (int k4 = 0; k4 < 64; k4 += 4) {
    float4 hv = *(const float4*)&rows[slot][k4];  // broadcast
    float4 wa = *(const float4*)&Wt[c0][k4];      // 2-way alias (free)
    float4 wb = *(const float4*)&Wt[c1][k4];
    o0 = fmaf(hv.x, wa.x, o0); o0 = fmaf(hv.y, wa.y, o0);
    o0 = fmaf(hv.z, wa.z, o0); o0 = fmaf(hv.w, wa.w, o0);
    o1 = fmaf(hv.x, wb.x, o1); o1 = fmaf(hv.y, wb.y, o1);
    o1 = fmaf(hv.z, wb.z, o1); o1 = fmaf(hv.w, wb.w, o1);
  }

  if (MODE == 1) {
    o0 *= dv; o1 *= dv;
    __half2 hh = __floats2half2_rn(o0, o1);
    ((__half2*)outp)[(size_t)d * 32 + sub] = hh;
  } else {
    float2 bp = ((const float2*)bpost)[sub];
    float2 o;
    o.x = fmaxf(o0 + bp.x, 0.f);
    o.y = fmaxf(o1 + bp.y, 0.f);
    ((float2*)outp)[(size_t)d * 32 + sub] = o;
  }
}

// fp32 GEMM for the MLP tail: C[n,F] = op(A[n,64])@W[64,F] (+bias)(relu).
// Single-phase only (see R6/R8 spill rule).
template <int F>
__global__ __launch_bounds__(256) void gemm_kernel(const float* __restrict__ A, const float* __restrict__ W,
                                                   const float* __restrict__ bias, float* __restrict__ C,
                                                   int n, int reluIn, int reluOut) {
  constexpr int CPT = F / 8;
  __shared__ float Ws[64 * F];
  int t = threadIdx.x;
  for (int i = t; i < 64 * F / 4; i += 256) ((float4*)Ws)[i] = ((const float4*)W)[i];
  __syncthreads();

  int rg = t >> 3, cg = t & 7;
  int r0 = blockIdx.x * 128 + rg * 4;
  int c0 = cg * CPT;

  float acc[4][CPT];
#pragma unroll
  for (int i = 0; i < 4; i++)
#pragma unroll
    for (int j = 0; j < CPT; j++) acc[i][j] = 0.f;

  const float4* A4 = (const float4*)A;
  for (int kk = 0; kk < 16; kk++) {
    float4 a[4];
#pragma unroll
    for (int i = 0; i < 4; i++) {
      int r = r0 + i;
      float4 v = (r < n) ? A4[(size_t)r * 16 + kk] : make_float4(0.f, 0.f, 0.f, 0.f);
      if (reluIn) {
        v.x = fmaxf(v.x, 0.f); v.y = fmaxf(v.y, 0.f);
        v.z = fmaxf(v.z, 0.f); v.w = fmaxf(v.w, 0.f);
      }
      a[i] = v;
    }
#pragma unroll
    for (int q = 0; q < 4; q++) {
      int k = kk * 4 + q;
      float w[CPT];
      if constexpr (CPT % 4 == 0) {
#pragma unroll
        for (int j = 0; j < CPT / 4; j++)
          *(float4*)&w[4 * j] = *(const float4*)&Ws[k * F + c0 + 4 * j];  // ds_read_b128
      } else {
#pragma unroll
        for (int j = 0; j < CPT; j++) w[j] = Ws[k * F + c0 + j];
      }
#pragma unroll
      for (int i = 0; i < 4; i++) {
        float av = q == 0 ? a[i].x : q == 1 ? a[i].y : q == 2 ? a[i].z : a[i].w;
#pragma unroll
        for (int j = 0; j < CPT; j++) acc[i][j] = fmaf(av, w[j], acc[i][j]);
      }
    }
  }

  float bv[CPT];
#pragma unroll
  for (int j = 0; j < CPT; j++) bv[j] = bias ? bias[c0 + j] : 0.f;
#pragma unroll
  for (int i = 0; i < 4; i++) {
    int r = r0 + i;
    if (r < n) {
      float* crow = C + (size_t)r * F + c0;
#pragma unroll
      for (int j = 0; j < CPT; j++) {
        float v = acc[i][j] + bv[j];
        if (reluOut) v = fmaxf(v, 0.f);
        crow[j] = v;
      }
    }
  }
}

}  // namespace

extern "C" void kernel_launch(void* const* d_in, const int* in_sizes, int n_in,
                              void* d_out, int out_size, void* d_ws, size_t ws_size,
                              hipStream_t stream) {
  const float* x   = (const float*)d_in[0];
  const void*  ei  = d_in[1];
  const float* W1  = (const float*)d_in[2];
  const float* b1  = (const float*)d_in[3];
  const float* W2  = (const float*)d_in[4];
  const float* b2  = (const float*)d_in[5];
  const float* Wm1 = (const float*)d_in[6];
  const float* bm1 = (const float*)d_in[7];
  const float* Wm2 = (const float*)d_in[8];
  const float* bm2 = (const float*)d_in[9];
  float* out = (float*)d_out;

  char* ws = (char*)d_ws;
  size_t off = 0;
  auto alloc = [&](size_t bytes) -> void* {
    void* p = ws + off;
    off = (off + bytes + 511) & ~(size_t)511;
    return p;
  };
  int*      bucketCnt = (int*)     alloc((size_t)NBUCK * 4);
  unsigned* tmp       = (unsigned*)alloc((size_t)NBUCK * CAP_RAW * 4);  // 6.4 MB
  int*      colA      = (int*)     alloc((size_t)NBUCK * CAP_COL * 4);  // 9.6 MB
  int*      rowS      = (int*)     alloc((size_t)N_NODES * 4);
  int*      rowE      = (int*)     alloc((size_t)N_NODES * 4);
  float*    dinv      = (float*)   alloc((size_t)N_NODES * 4);
  __half*   g1        = (__half*)  alloc((size_t)(N_NODES + 1) * 64 * 2);  // +1 zero row
  __half*   gB        = (__half*)  alloc((size_t)(N_NODES + 1) * 64 * 2);  // conv2 table
  float*    hA        = (float*)   alloc((size_t)N_NODES * 64 * 4);
  (void)ws_size; (void)in_sizes; (void)n_in; (void)out_size;

  dim3 b256(256);
  int gGemm = (N_NODES + 127) / 128;
  int gAgg  = N_NODES / 8;  // 12500, exact
  int gBkt  = (N_EDGES + EPB_A - 1) / EPB_A;

  // preprocessing: 2-pass bucket sort -> padded CSR (shared by both convs)
  hipMemsetAsync(bucketCnt, 0, (size_t)NBUCK * 4, stream);
  bucket_kernel<<<gBkt, b256, 0, stream>>>(ei, bucketCnt, tmp);
  csr_kernel<<<NBUCK, dim3(512), 0, stream>>>(tmp, bucketCnt, colA, rowS, rowE, dinv);

  // conv1 tables: g1 = (x@W1)*dinv (fp16); also zeroes both pad rows
  gemm_g_kernel<<<gGemm, b256, 0, stream>>>(x, W1, dinv, g1, gB, 0);

  // conv1 aggregate + fused conv2 gemm: gB = (relu(dinv*(self+sum)+b1)@W2)*dinv
  agg_fused<1><<<gAgg, b256, 0, stream>>>(g1, colA, rowS, rowE, dinv, b1, W2, nullptr, gB);

  // conv2 aggregate + fused MLP-1: hA = relu((dinv*(self+sum)+b2)@Wm1 + bm1)
  agg_fused<2><<<gAgg, b256, 0, stream>>>(gB, colA, rowS, rowE, dinv, b2, Wm1, bm1, hA);

  // MLP tail: out = hA@Wm2+bm2
  gemm_kernel<40><<<gGemm, b256, 0, stream>>>(hA, Wm2, bm2, out, N_NODES, 0, 0);
}

// Round 6
// 269.455 us; speedup vs baseline: 1.0128x; 1.0128x over previous
//
#include <hip/hip_runtime.h>
#include <hip/hip_bf16.h>
#include <hip/hip_fp16.h>

// GCN: h1 = relu(GCNConv(x,W1,b1)); h2 = GCNConv(h1,W2,b2);
//      h3 = relu(h2@Wm1+bm1); out = h3@Wm2+bm2
// R2: CSR-by-dst gather-reduce replaced scatter atomics (10x write amp).
// R4: 2-pass XCD-local bucket sort. R5: dinv folded into GEMM epilogue.
// R6/R8 FAILED: multi-phase LDS GEMM fusion -> spills. R7: fp16 g-tables.
// R9: 2-node/wave aggregate, 8-deep (255.8us). R13 FAILED: 4-deep (263us).
// R14: cleanup (253.7us). R15 FAILED (1071us): scatter-side LDS agg.
// R16 FAILED (268.5us): perm pairing. R17 NEUTRAL (252.2us): depth 16.
// R18 WIN (249.0us): per-row 64x64 GEMM fused into aggregate epilogues
//      (agg 53.7us, VALU 43%, HBM 20%, occ 60%; issue-bound, no pipe sat).
// R19 FAILED (272.9us): dual-row b64 gathers + Wt b128 at col-stride-2 ->
//      6.4M LDS bank-conflict cycles (~10us/dispatch; the +1 pad only helps
//      CONSECUTIVE-column lanes) + cndmask VALU. TA model untested-clean.
// R20: wide-lane gathers, conflict-free epilogue.
//      (a) half-wave = node = 4 groups x 8 lanes; lane loads uint4 (8 feats)
//          -> ONE gather instr fetches 8 edge-rows; per 16-edge trip:
//          1 int4 col load + 4 gathers = 5 vmem vs R18's 20 (TA model:
//          64-lane vmem instr ~ 16 addr-cycles regardless of lines).
//          Rows in flight/trip = 16 >= R9-proven 8. Reduce: shfl_xor(8,16).
//      (b) epilogue: lane computes cols (sub, sub+32) from Wt[64][65] b128
//          -> lane stride 65 == 1 bank -> conflict-free; W reads broadcast
//          across the wave's 2 nodes.

namespace {

constexpr int N_NODES = 100000;
constexpr int N_EDGES = 1000000;
constexpr int NBUCK = (N_NODES + 511) / 512;  // 196 buckets of 512 nodes
constexpr int CAP_RAW = 8192;   // raw edges/bucket (mean 5120, sd ~71)
constexpr int CAP_COL = 12288;  // pad-16 edges/bucket (mean ~8400, sd ~80)
constexpr int EPB_A = 2048;     // edges per passA block

// passA: partition edges into NBUCK buckets by dst>>9. word=(src<<9)|(dst&511).
__global__ __launch_bounds__(256) void bucket_kernel(const void* __restrict__ ei,
                                                     int* __restrict__ bucketCnt,
                                                     unsigned* __restrict__ tmp) {
  __shared__ int hist[NBUCK];
  __shared__ int basePB[NBUCK];
  __shared__ int cur[NBUCK];
  __shared__ int sflag;
  int t = threadIdx.x;
  if (t < NBUCK) { hist[t] = 0; cur[t] = 0; }
  if (t == 0) sflag = 0;
  __syncthreads();

  int e0 = blockIdx.x * EPB_A;
  const unsigned* w = (const unsigned*)ei;
  unsigned any = 0;
#pragma unroll
  for (int s = 0; s < 2; s++) {
    int e = e0 + s * 256 + t;
    if (e < N_EDGES) any |= w[2 * e + 1];
  }
  if (any) sflag = 1;  // benign race, all writers store 1
  __syncthreads();
  int is32 = sflag;

  unsigned wreg[8];
  int breg[8];
#pragma unroll
  for (int k = 0; k < 8; k++) {
    int e = e0 + k * 256 + t;
    breg[k] = -1;
    if (e < N_EDGES) {
      int s, d;
      if (is32) {
        const int* p = (const int*)ei;
        s = p[e]; d = p[N_EDGES + e];
      } else {
        const long long* p = (const long long*)ei;
        s = (int)p[e]; d = (int)p[N_EDGES + e];
      }
      wreg[k] = ((unsigned)s << 9) | (unsigned)(d & 511);
      breg[k] = d >> 9;
      atomicAdd(&hist[breg[k]], 1);
    }
  }
  __syncthreads();
  if (t < NBUCK) basePB[t] = hist[t] ? atomicAdd(&bucketCnt[t], hist[t]) : 0;
  __syncthreads();
#pragma unroll
  for (int k = 0; k < 8; k++) {
    if (breg[k] >= 0) {
      int r = atomicAdd(&cur[breg[k]], 1);
      tmp[(size_t)breg[k] * CAP_RAW + basePB[breg[k]] + r] = wreg[k];
    }
  }
}

// passB: one block per bucket. LDS counting sort; rows padded to mult 16 with
// sentinel N_NODES (zero row); emit row_start/row_end + dinv.
__global__ __launch_bounds__(512) void csr_kernel(const unsigned* __restrict__ tmp,
                                                  const int* __restrict__ bucketCnt,
                                                  int* __restrict__ col,
                                                  int* __restrict__ row_start,
                                                  int* __restrict__ row_end,
                                                  float* __restrict__ dinv) {
  __shared__ int sc[512];
  __shared__ int hist[512];
  __shared__ unsigned stage[CAP_RAW];
  int b = blockIdx.x, t = threadIdx.x;
  int myCnt = bucketCnt[b];
  int baseT = b * CAP_RAW;
  int baseC = b * CAP_COL;

  hist[t] = 0;
  __syncthreads();
  for (int i = t; i < myCnt; i += 512) {
    unsigned w = tmp[(size_t)baseT + i];
    stage[i] = w;
    atomicAdd(&hist[w & 511u], 1);
  }
  __syncthreads();

  int deg = hist[t];
  int pdeg = (deg + 15) & ~15;  // pad rows to mult 16 (16 rows/trip in flight)
  sc[t] = pdeg;
  __syncthreads();
#pragma unroll
  for (int off = 1; off < 512; off <<= 1) {
    int u = (t >= off) ? sc[t - off] : 0;
    __syncthreads();
    sc[t] += u;
    __syncthreads();
  }
  int pexcl = sc[t] - pdeg;
  int d = b * 512 + t;
  if (d < N_NODES) {
    row_start[d] = baseC + pexcl;
    row_end[d] = baseC + pexcl + pdeg;
    dinv[d] = rsqrtf((float)deg + 1.0f);
  }
  __syncthreads();
  hist[t] = pexcl;
  __syncthreads();
  for (int i = t; i < myCnt; i += 512) {
    unsigned w = stage[i];
    int pos = atomicAdd(&hist[w & 511u], 1);
    col[baseC + pos] = (int)(w >> 9);
  }
  for (int j = deg; j < pdeg; j++) col[baseC + pexcl + j] = N_NODES;
}

__device__ inline uint4 pack_half8(const float* v) {
  __half2 h0 = __floats2half2_rn(v[0], v[1]);
  __half2 h1 = __floats2half2_rn(v[2], v[3]);
  __half2 h2 = __floats2half2_rn(v[4], v[5]);
  __half2 h3 = __floats2half2_rn(v[6], v[7]);
  uint4 u;
  u.x = *(unsigned*)&h0; u.y = *(unsigned*)&h1;
  u.z = *(unsigned*)&h2; u.w = *(unsigned*)&h3;
  return u;
}

// g[r] = (op(A[r])@W) * dinv[r], fp16 out, zero pad row N_NODES.
// 128 rows/block, 256 thr, thread = 4 rows x 8 cols. W staged in LDS.
__global__ __launch_bounds__(256) void gemm_g_kernel(const float* __restrict__ A,
                                                     const float* __restrict__ W,
                                                     const float* __restrict__ dinv,
                                                     __half* __restrict__ g,
                                                     __half* __restrict__ gpad2,
                                                     int reluIn) {
  __shared__ float Ws[64 * 64];
  int t = threadIdx.x;
  if (blockIdx.x == 0 && t < 32) {
    ((float*)(g + (size_t)N_NODES * 64))[t] = 0.f;  // pad row (this table)
    if (gpad2) ((float*)(gpad2 + (size_t)N_NODES * 64))[t] = 0.f;  // pad row (agg1 output table)
  }
  for (int i = t; i < 64 * 64 / 4; i += 256) ((float4*)Ws)[i] = ((const float4*)W)[i];
  __syncthreads();

  int rg = t >> 3, cg = t & 7;
  int r0 = blockIdx.x * 128 + rg * 4;
  int c0 = cg * 8;

  float acc[4][8];
#pragma unroll
  for (int i = 0; i < 4; i++)
#pragma unroll
    for (int j = 0; j < 8; j++) acc[i][j] = 0.f;

  const float4* A4 = (const float4*)A;
  for (int kk = 0; kk < 16; kk++) {
    float4 a[4];
#pragma unroll
    for (int i = 0; i < 4; i++) {
      int r = r0 + i;
      float4 v = (r < N_NODES) ? A4[(size_t)r * 16 + kk] : make_float4(0.f, 0.f, 0.f, 0.f);
      if (reluIn) {
        v.x = fmaxf(v.x, 0.f); v.y = fmaxf(v.y, 0.f);
        v.z = fmaxf(v.z, 0.f); v.w = fmaxf(v.w, 0.f);
      }
      a[i] = v;
    }
#pragma unroll
    for (int q = 0; q < 4; q++) {
      int k = kk * 4 + q;
      float w[8];
#pragma unroll
      for (int j = 0; j < 2; j++) *(float4*)&w[4 * j] = *(const float4*)&Ws[k * 64 + c0 + 4 * j];
#pragma unroll
      for (int i = 0; i < 4; i++) {
        float av = q == 0 ? a[i].x : q == 1 ? a[i].y : q == 2 ? a[i].z : a[i].w;
#pragma unroll
        for (int j = 0; j < 8; j++) acc[i][j] = fmaf(av, w[j], acc[i][j]);
      }
    }
  }
#pragma unroll
  for (int i = 0; i < 4; i++) {
    int r = r0 + i;
    if (r < N_NODES) {
      float s = dinv[r];
#pragma unroll
      for (int j = 0; j < 8; j++) acc[i][j] *= s;
      *(uint4*)(g + (size_t)r * 64 + c0) = pack_half8(acc[i]);
    }
  }
}

// Fused gather-aggregate + per-row 64x64 GEMM epilogue (R20).
// Gather: half-wave = 1 node = 4 groups x 8 lanes. Lane loads uint4 (8 feats,
// 16B); one gather instr fetches 8 edge-rows (4/half-wave x 2 halves). Per
// 16-edge trip: 1 int4 col load (lane's group picks its 4 edges) + 4 gathers.
// 16 rows in flight. Cross-group reduce: shfl_xor(8)+(16); self added after.
// Epilogue: row staged in per-half-wave LDS slot by group-0 lanes; lane
// computes cols (sub, sub+32) from transposed Wt[64][65] b128 (stride 65 ==
// 1 bank -> conflict-free; broadcast across the wave's two nodes).
// MODE 1 (conv1 -> conv2 g-table): relu pre-GEMM, *dinv post, fp16 out.
// MODE 2 (conv2 -> MLP hidden):    no pre-relu, +bpost then relu, fp32 out.
template <int MODE>
__global__ __launch_bounds__(256) void agg_fused(const __half* __restrict__ g,
                                                 const int* __restrict__ col,
                                                 const int* __restrict__ row_start,
                                                 const int* __restrict__ row_end,
                                                 const float* __restrict__ dinv,
                                                 const float* __restrict__ bconv,
                                                 const float* __restrict__ W,
                                                 const float* __restrict__ bpost,
                                                 void* __restrict__ outp) {
  __shared__ float Wt[64][65];    // transposed+padded: Wt[c][k] = W[k][c]
  __shared__ float rows[8][64];   // one row slot per half-wave
  int t = threadIdx.x;
  for (int i = t; i < 64 * 64; i += 256) {
    int k = i >> 6, c = i & 63;
    Wt[c][k] = W[i];  // coalesced global read; stride-65 LDS write, no conflict
  }
  __syncthreads();

  int wave = t >> 6;
  int lane = t & 63;
  int half = lane >> 5;
  int sub = lane & 31;
  int grp = sub >> 3;   // gather group 0..3 within half-wave
  int q = lane & 7;     // feat slice: feats 8q..8q+7
  int slot = t >> 5;    // half-wave id 0..7
  int d = blockIdx.x * 8 + wave * 2 + half;

  const uint4* g4 = (const uint4*)g;  // row r, slice q at g4[r*8 + q]
  int e0 = row_start[d];
  int len = row_end[d] - e0;

  float s0 = 0.f, s1 = 0.f, s2 = 0.f, s3 = 0.f;
  float s4 = 0.f, s5 = 0.f, s6 = 0.f, s7 = 0.f;

#define ACC8(u)                                           \
  {                                                       \
    float2 f0 = __half22float2(*(const __half2*)&(u).x);  \
    float2 f1 = __half22float2(*(const __half2*)&(u).y);  \
    float2 f2 = __half22float2(*(const __half2*)&(u).z);  \
    float2 f3 = __half22float2(*(const __half2*)&(u).w);  \
    s0 += f0.x; s1 += f0.y; s2 += f1.x; s3 += f1.y;       \
    s4 += f2.x; s5 += f2.y; s6 += f3.x; s7 += f3.y;       \
  }

  for (int i = 0; i < len; i += 16) {  // per-half-wave trip count
    int4 ce = *(const int4*)(col + e0 + i + 4 * grp);  // group's 4 edges
    uint4 u0 = g4[(size_t)ce.x * 8 + q];
    uint4 u1 = g4[(size_t)ce.y * 8 + q];
    uint4 u2 = g4[(size_t)ce.z * 8 + q];
    uint4 u3 = g4[(size_t)ce.w * 8 + q];
    ACC8(u0) ACC8(u1) ACC8(u2) ACC8(u3)
  }
  // reduce across the 4 groups (bits 3,4 of lane); stays within half-wave
  s0 += __shfl_xor(s0, 8, 64);  s1 += __shfl_xor(s1, 8, 64);
  s2 += __shfl_xor(s2, 8, 64);  s3 += __shfl_xor(s3, 8, 64);
  s4 += __shfl_xor(s4, 8, 64);  s5 += __shfl_xor(s5, 8, 64);
  s6 += __shfl_xor(s6, 8, 64);  s7 += __shfl_xor(s7, 8, 64);
  s0 += __shfl_xor(s0, 16, 64); s1 += __shfl_xor(s1, 16, 64);
  s2 += __shfl_xor(s2, 16, 64); s3 += __shfl_xor(s3, 16, 64);
  s4 += __shfl_xor(s4, 16, 64); s5 += __shfl_xor(s5, 16, 64);
  s6 += __shfl_xor(s6, 16, 64); s7 += __shfl_xor(s7, 16, 64);
  {  // self row (dinv already folded into g); add AFTER reduce (once)
    uint4 us = g4[(size_t)d * 8 + q];
    ACC8(us)
  }
#undef ACC8

  float dv = dinv[d];
  float4 bv0 = *(const float4*)&bconv[8 * q];
  float4 bv1 = *(const float4*)&bconv[8 * q + 4];
  float h0 = fmaf(s0, dv, bv0.x), h1 = fmaf(s1, dv, bv0.y);
  float h2 = fmaf(s2, dv, bv0.z), h3 = fmaf(s3, dv, bv0.w);
  float h4 = fmaf(s4, dv, bv1.x), h5 = fmaf(s5, dv, bv1.y);
  float h6 = fmaf(s6, dv, bv1.z), h7 = fmaf(s7, dv, bv1.w);
  if (MODE == 1) {
    h0 = fmaxf(h0, 0.f); h1 = fmaxf(h1, 0.f); h2 = fmaxf(h2, 0.f); h3 = fmaxf(h3, 0.f);
    h4 = fmaxf(h4, 0.f); h5 = fmaxf(h5, 0.f); h6 = fmaxf(h6, 0.f); h7 = fmaxf(h7, 0.f);
  }

  // stage row (group-0 lanes; wave-synchronous, same-wave LDS ordering)
  if (grp == 0) {
    *(float4*)&rows[slot][8 * q] = make_float4(h0, h1, h2, h3);
    *(float4*)&rows[slot][8 * q + 4] = make_float4(h4, h5, h6, h7);
  }

  // epilogue matvec: lane computes cols (sub, sub+32); conflict-free b128.
  float o0 = 0.f, o1 = 0.f;
  int c0 = sub, c1 = sub + 32;
#pragma unroll 4
  for (int k4 = 0; k4 < 64; k4 += 4) {
    float4 hv = *(const float4*)&rows[slot][k4];  // broadcast
    float4 wa = *(const float4*)&Wt[c0][k4];      // stride 65 -> all 32 banks
    float4 wb = *(const float4*)&Wt[c1][k4];
    o0 = fmaf(hv.x, wa.x, o0); o0 = fmaf(hv.y, wa.y, o0);
    o0 = fmaf(hv.z, wa.z, o0); o0 = fmaf(hv.w, wa.w, o0);
    o1 = fmaf(hv.x, wb.x, o1); o1 = fmaf(hv.y, wb.y, o1);
    o1 = fmaf(hv.z, wb.z, o1); o1 = fmaf(hv.w, wb.w, o1);
  }

  if (MODE == 1) {
    o0 *= dv; o1 *= dv;
    __half* gp = (__half*)outp;
    gp[(size_t)d * 64 + sub] = __float2half(o0);
    gp[(size_t)d * 64 + sub + 32] = __float2half(o1);
  } else {
    float* op = (float*)outp;
    op[(size_t)d * 64 + sub] = fmaxf(o0 + bpost[sub], 0.f);
    op[(size_t)d * 64 + sub + 32] = fmaxf(o1 + bpost[sub + 32], 0.f);
  }
}

// fp32 GEMM for the MLP tail: C[n,F] = op(A[n,64])@W[64,F] (+bias)(relu).
// Single-phase only (see R6/R8 spill rule).
template <int F>
__global__ __launch_bounds__(256) void gemm_kernel(const float* __restrict__ A, const float* __restrict__ W,
                                                   const float* __restrict__ bias, float* __restrict__ C,
                                                   int n, int reluIn, int reluOut) {
  constexpr int CPT = F / 8;
  __shared__ float Ws[64 * F];
  int t = threadIdx.x;
  for (int i = t; i < 64 * F / 4; i += 256) ((float4*)Ws)[i] = ((const float4*)W)[i];
  __syncthreads();

  int rg = t >> 3, cg = t & 7;
  int r0 = blockIdx.x * 128 + rg * 4;
  int c0 = cg * CPT;

  float acc[4][CPT];
#pragma unroll
  for (int i = 0; i < 4; i++)
#pragma unroll
    for (int j = 0; j < CPT; j++) acc[i][j] = 0.f;

  const float4* A4 = (const float4*)A;
  for (int kk = 0; kk < 16; kk++) {
    float4 a[4];
#pragma unroll
    for (int i = 0; i < 4; i++) {
      int r = r0 + i;
      float4 v = (r < n) ? A4[(size_t)r * 16 + kk] : make_float4(0.f, 0.f, 0.f, 0.f);
      if (reluIn) {
        v.x = fmaxf(v.x, 0.f); v.y = fmaxf(v.y, 0.f);
        v.z = fmaxf(v.z, 0.f); v.w = fmaxf(v.w, 0.f);
      }
      a[i] = v;
    }
#pragma unroll
    for (int q = 0; q < 4; q++) {
      int k = kk * 4 + q;
      float w[CPT];
      if constexpr (CPT % 4 == 0) {
#pragma unroll
        for (int j = 0; j < CPT / 4; j++)
          *(float4*)&w[4 * j] = *(const float4*)&Ws[k * F + c0 + 4 * j];  // ds_read_b128
      } else {
#pragma unroll
        for (int j = 0; j < CPT; j++) w[j] = Ws[k * F + c0 + j];
      }
#pragma unroll
      for (int i = 0; i < 4; i++) {
        float av = q == 0 ? a[i].x : q == 1 ? a[i].y : q == 2 ? a[i].z : a[i].w;
#pragma unroll
        for (int j = 0; j < CPT; j++) acc[i][j] = fmaf(av, w[j], acc[i][j]);
      }
    }
  }

  float bv[CPT];
#pragma unroll
  for (int j = 0; j < CPT; j++) bv[j] = bias ? bias[c0 + j] : 0.f;
#pragma unroll
  for (int i = 0; i < 4; i++) {
    int r = r0 + i;
    if (r < n) {
      float* crow = C + (size_t)r * F + c0;
#pragma unroll
      for (int j = 0; j < CPT; j++) {
        float v = acc[i][j] + bv[j];
        if (reluOut) v = fmaxf(v, 0.f);
        crow[j] = v;
      }
    }
  }
}

}  // namespace

extern "C" void kernel_launch(void* const* d_in, const int* in_sizes, int n_in,
                              void* d_out, int out_size, void* d_ws, size_t ws_size,
                              hipStream_t stream) {
  const float* x   = (const float*)d_in[0];
  const void*  ei  = d_in[1];
  const float* W1  = (const float*)d_in[2];
  const float* b1  = (const float*)d_in[3];
  const float* W2  = (const float*)d_in[4];
  const float* b2  = (const float*)d_in[5];
  const float* Wm1 = (const float*)d_in[6];
  const float* bm1 = (const float*)d_in[7];
  const float* Wm2 = (const float*)d_in[8];
  const float* bm2 = (const float*)d_in[9];
  float* out = (float*)d_out;

  char* ws = (char*)d_ws;
  size_t off = 0;
  auto alloc = [&](size_t bytes) -> void* {
    void* p = ws + off;
    off = (off + bytes + 511) & ~(size_t)511;
    return p;
  };
  int*      bucketCnt = (int*)     alloc((size_t)NBUCK * 4);
  unsigned* tmp       = (unsigned*)alloc((size_t)NBUCK * CAP_RAW * 4);  // 6.4 MB
  int*      colA      = (int*)     alloc((size_t)NBUCK * CAP_COL * 4);  // 9.6 MB
  int*      rowS      = (int*)     alloc((size_t)N_NODES * 4);
  int*      rowE      = (int*)     alloc((size_t)N_NODES * 4);
  float*    dinv      = (float*)   alloc((size_t)N_NODES * 4);
  __half*   g1        = (__half*)  alloc((size_t)(N_NODES + 1) * 64 * 2);  // +1 zero row
  __half*   gB        = (__half*)  alloc((size_t)(N_NODES + 1) * 64 * 2);  // conv2 table
  float*    hA        = (float*)   alloc((size_t)N_NODES * 64 * 4);
  (void)ws_size; (void)in_sizes; (void)n_in; (void)out_size;

  dim3 b256(256);
  int gGemm = (N_NODES + 127) / 128;
  int gAgg  = N_NODES / 8;  // 12500, exact
  int gBkt  = (N_EDGES + EPB_A - 1) / EPB_A;

  // preprocessing: 2-pass bucket sort -> padded CSR (shared by both convs)
  hipMemsetAsync(bucketCnt, 0, (size_t)NBUCK * 4, stream);
  bucket_kernel<<<gBkt, b256, 0, stream>>>(ei, bucketCnt, tmp);
  csr_kernel<<<NBUCK, dim3(512), 0, stream>>>(tmp, bucketCnt, colA, rowS, rowE, dinv);

  // conv1 tables: g1 = (x@W1)*dinv (fp16); also zeroes both pad rows
  gemm_g_kernel<<<gGemm, b256, 0, stream>>>(x, W1, dinv, g1, gB, 0);

  // conv1 aggregate + fused conv2 gemm: gB = (relu(dinv*(self+sum)+b1)@W2)*dinv
  agg_fused<1><<<gAgg, b256, 0, stream>>>(g1, colA, rowS, rowE, dinv, b1, W2, nullptr, gB);

  // conv2 aggregate + fused MLP-1: hA = relu((dinv*(self+sum)+b2)@Wm1 + bm1)
  agg_fused<2><<<gAgg, b256, 0, stream>>>(gB, colA, rowS, rowE, dinv, b2, Wm1, bm1, hA);

  // MLP tail: out = hA@Wm2+bm2
  gemm_kernel<40><<<gGemm, b256, 0, stream>>>(hA, Wm2, bm2, out, N_NODES, 0, 0);
}